// Round 2
// baseline (1494.947 us; speedup 1.0000x reference)
//
#include <hip/hip_runtime.h>
#include <cfloat>

// Problem dims (fixed): z_e [32,64,64,64] NCHW fp32, embedding [1024,64] fp32
// Flat rows n = b*4096 + h*64 + w  (N = 131072, D = 64, K = 1024)
// Out layout (concat, fp32): [0]=vq_loss, [1..8388608]=z_q NCHW,
//                            [8388609]=perplexity, [8388610..]=encodings [N,1024]
// ws layout: ws[0]=loss accum (float), ws[1..1024]=counts (int), ws[1025..2048]=e2 (float)

__global__ __launch_bounds__(256) void vq_prep(const float* __restrict__ emb,
                                               float* __restrict__ ws) {
  #pragma clang fp contract(off)
  int gid = blockIdx.x * 256 + threadIdx.x;   // 0..1023
  if (gid == 0) ws[0] = 0.0f;
  ((int*)ws)[1 + gid] = 0;
  // e2[k] = numpy-pairwise sum of squares over 64 elems
  const float* e = emb + (gid << 6);
  float r[8];
  #pragma unroll
  for (int j = 0; j < 8; ++j) r[j] = e[j] * e[j];
  #pragma unroll
  for (int i = 8; i < 64; i += 8) {
    #pragma unroll
    for (int j = 0; j < 8; ++j) { float s = e[i + j] * e[i + j]; r[j] = r[j] + s; }
  }
  ws[1025 + gid] = ((r[0] + r[1]) + (r[2] + r[3])) + ((r[4] + r[5]) + (r[6] + r[7]));
}

// Block = 4 waves = one 64-row group (b,h). Wave w scans k-slice [256w, 256w+256).
// __launch_bounds__(256,4): 4 waves/EU -> up to 128 VGPRs, so x[64] stays in regs.
__global__ __launch_bounds__(256, 4) void vq_main(const float* __restrict__ ze,
                                                  const float* __restrict__ emb,
                                                  float* __restrict__ ws,
                                                  float* __restrict__ out) {
  __shared__ float sdist[4][64];
  __shared__ int   sidx[4][64];

  int w    = threadIdx.x >> 6;   // k-slice 0..3
  int lane = threadIdx.x & 63;   // row within group (= spatial w coord)
  int g    = blockIdx.x;         // row group 0..2047
  int b = g >> 6, h = g & 63;
  int n0 = g << 6;               // first flat row of this group

  // ---- load x[64]: z_e[b, d, h, w], coalesced along w per d ----
  const float* xin = ze + (b << 18) + (h << 6) + lane;
  float x[64];
  #pragma unroll
  for (int d = 0; d < 64; ++d) x[d] = xin[d << 12];

  // ---- x2: replicate numpy pairwise-sum order exactly ----
  float x2;
  {
    #pragma clang fp contract(off)
    float r[8];
    #pragma unroll
    for (int j = 0; j < 8; ++j) r[j] = x[j] * x[j];
    #pragma unroll
    for (int i = 8; i < 64; i += 8) {
      #pragma unroll
      for (int j = 0; j < 8; ++j) { float s = x[i + j] * x[i + j]; r[j] = r[j] + s; }
    }
    x2 = ((r[0] + r[1]) + (r[2] + r[3])) + ((r[4] + r[5]) + (r[6] + r[7]));
  }

  const float* e2w = ws + 1025;
  float* zq  = out + 1;
  float* enc = out + 8388610;

  int k0 = w << 8;               // slice base
  const float4* E4 = (const float4*)emb;

  // zero-stream: wave w zeroes enc[n0+r][k0 .. k0+256) for r=0..63.
  // 64 rows * 128 float2 = 8192 float2 / 64 lanes = 128 stores/lane,
  // cadence 1 store per k2 (2 codes). Per k2: r = k2>>1, c = (k2&1)*64 + lane
  // -> 64 lanes * 8B = 512B contiguous per store instruction.
  float2* encz = (float2*)enc + ((size_t)n0 << 9) + (w << 7) + lane;
  const float2 z2 = make_float2(0.0f, 0.0f);

  float best = FLT_MAX;
  int bidx = k0;

  for (int k2 = 0; k2 < 128; ++k2) {
    #pragma unroll
    for (int u = 0; u < 2; ++u) {
      int k = k0 + (k2 << 1) + u;
      const float4* ek = E4 + (k << 4);  // wave-uniform -> s_load
      float a0 = 0.0f, a1 = 0.0f, a2 = 0.0f, a3 = 0.0f;
      #pragma unroll
      for (int j = 0; j < 16; ++j) {
        float4 ev = ek[j];
        a0 = fmaf(x[(j << 2) + 0], ev.x, a0);
        a1 = fmaf(x[(j << 2) + 1], ev.y, a1);
        a2 = fmaf(x[(j << 2) + 2], ev.z, a2);
        a3 = fmaf(x[(j << 2) + 3], ev.w, a3);
      }
      float acc  = (a0 + a1) + (a2 + a3);
      float t    = x2 + e2w[k];          // fl(x2 + e2) like numpy broadcast
      float dist = fmaf(-2.0f, acc, t);  // == fl(t - fl(2*acc)); 2*acc exact
      if (dist < best) { best = dist; bidx = k; }  // strict < = first-index
    }
    encz[((size_t)(k2 >> 1) << 9) + ((k2 & 1) << 6)] = z2;
  }

  // ---- cross-wave argmin combine (slices are k-ordered; strict < keeps
  //      the lowest-k winner on ties, matching numpy first-index argmin) ----
  sdist[w][lane] = best;
  sidx[w][lane]  = bidx;
  __syncthreads();   // also drains all zero-stream stores (vmcnt(0) pre-barrier)

  float gb = sdist[0][lane];
  int   gi = sidx[0][lane];
  #pragma unroll
  for (int j = 1; j < 4; ++j) {
    float dj = sdist[j][lane];
    int   ij = sidx[j][lane];
    if (dj < gb) { gb = dj; gi = ij; }
  }

  // ---- epilogue, split across waves: wave w handles d in [16w, 16w+16) ----
  const float* esel = emb + (gi << 6);
  float* zqp = zq + (b << 18) + (h << 6) + lane;
  float lsum = 0.0f;
  #pragma unroll
  for (int dd = 0; dd < 16; ++dd) {
    int d = (w << 4) + dd;
    float v = esel[d];            // per-lane gather, 256KB table (L2-resident)
    float df = v - x[d];
    lsum = fmaf(df, df, lsum);
    zqp[d << 12] = v;             // coalesced along w
  }
  #pragma unroll
  for (int off = 32; off > 0; off >>= 1) lsum += __shfl_down(lsum, off, 64);
  if (lane == 0) atomicAdd(ws, lsum);
  if (w == 0) atomicAdd(&((int*)ws)[1 + gi], 1);

  // one-hot 1.0: written by the wave that owns the winning slice, so the
  // zero store to the same address is same-wave and already drained at the
  // barrier above. Explicit drain again is belt-and-braces (epilogue stores).
  if ((gi >> 8) == w) {
    asm volatile("s_waitcnt vmcnt(0)" ::: "memory");
    enc[((size_t)(n0 + lane) << 10) + gi] = 1.0f;
  }
}

__global__ __launch_bounds__(1024) void vq_fin(const float* __restrict__ ws,
                                               float* __restrict__ out) {
  __shared__ float sm[16];
  int t = threadIdx.x;  // 0..1023 = k
  const int* counts = (const int*)ws + 1;
  float c = (float)counts[t];
  float p = c * (1.0f / 131072.0f);
  float s = p * logf(p + 1e-10f);
  #pragma unroll
  for (int off = 32; off > 0; off >>= 1) s += __shfl_down(s, off, 64);
  if ((t & 63) == 0) sm[t >> 6] = s;
  __syncthreads();
  if (t == 0) {
    float v = 0.0f;
    #pragma unroll
    for (int i = 0; i < 16; ++i) v += sm[i];
    out[8388609] = expf(-v);               // perplexity
    float m = ws[0] / 8388608.0f;          // mean (z_q - z)^2
    out[0] = 0.25f * m + m;                // commitment + e2z
  }
}

extern "C" void kernel_launch(void* const* d_in, const int* in_sizes, int n_in,
                              void* d_out, int out_size, void* d_ws, size_t ws_size,
                              hipStream_t stream) {
  const float* ze  = (const float*)d_in[0];
  const float* emb = (const float*)d_in[1];
  float* out = (float*)d_out;
  float* ws  = (float*)d_ws;   // needs 2049 * 4B ≈ 8.2 KB
  vq_prep<<<4, 256, 0, stream>>>(emb, ws);
  vq_main<<<2048, 256, 0, stream>>>(ze, emb, ws, out);
  vq_fin<<<1, 1024, 0, stream>>>(ws, out);
}

// Round 3
// 1143.876 us; speedup vs baseline: 1.3069x; 1.3069x over previous
//
#include <hip/hip_runtime.h>
#include <cfloat>

// Problem dims (fixed): z_e [32,64,64,64] NCHW fp32, embedding [1024,64] fp32
// Flat rows n = b*4096 + h*64 + w  (N = 131072, D = 64, K = 1024)
// Out layout (concat, fp32): [0]=vq_loss, [1..8388608]=z_q NCHW,
//                            [8388609]=perplexity, [8388610..]=encodings [N,1024]
// ws layout: ws[0]=loss accum (float), ws[1..1024]=counts (int), ws[1025..2048]=e2 (float)

__global__ __launch_bounds__(256) void vq_prep(const float* __restrict__ emb,
                                               float* __restrict__ ws) {
  #pragma clang fp contract(off)
  int gid = blockIdx.x * 256 + threadIdx.x;   // 0..1023
  if (gid == 0) ws[0] = 0.0f;
  ((int*)ws)[1 + gid] = 0;
  // e2[k] = numpy-pairwise sum of squares over 64 elems
  const float* e = emb + (gid << 6);
  float r[8];
  #pragma unroll
  for (int j = 0; j < 8; ++j) r[j] = e[j] * e[j];
  #pragma unroll
  for (int i = 8; i < 64; i += 8) {
    #pragma unroll
    for (int j = 0; j < 8; ++j) { float s = e[i + j] * e[i + j]; r[j] = r[j] + s; }
  }
  ws[1025 + gid] = ((r[0] + r[1]) + (r[2] + r[3])) + ((r[4] + r[5]) + (r[6] + r[7]));
}

// One wave per 64-row group (b,h); wave scans ALL 1024 codes.
// CRITICAL: emb/e2 addresses depend only on the loop counter -> block-uniform
// -> s_load into SGPRs. All x[] indices are compile-time -> SROA to VGPRs.
// __launch_bounds__(256,4): VGPR cap 128 so x[64] stays resident.
__global__ __launch_bounds__(256, 4) void vq_main(const float* __restrict__ ze,
                                                  const float* __restrict__ emb,
                                                  float* __restrict__ ws,
                                                  float* __restrict__ out) {
  int wave = (blockIdx.x << 2) + (threadIdx.x >> 6);  // 0..2047
  int lane = threadIdx.x & 63;                        // = w
  int b = wave >> 6;
  int h = wave & 63;

  // ---- load x[64]: z_e[b, d, h, w], coalesced along w per d ----
  const float* xin = ze + (b << 18) + (h << 6) + lane;
  float x[64];
  #pragma unroll
  for (int d = 0; d < 64; ++d) x[d] = xin[d << 12];

  // ---- x2: replicate numpy pairwise-sum order exactly ----
  float x2;
  {
    #pragma clang fp contract(off)
    float r[8];
    #pragma unroll
    for (int j = 0; j < 8; ++j) r[j] = x[j] * x[j];
    #pragma unroll
    for (int i = 8; i < 64; i += 8) {
      #pragma unroll
      for (int j = 0; j < 8; ++j) { float s = x[i + j] * x[i + j]; r[j] = r[j] + s; }
    }
    x2 = ((r[0] + r[1]) + (r[2] + r[3])) + ((r[4] + r[5]) + (r[6] + r[7]));
  }

  const float* e2w = ws + 1025;
  float* zq  = out + 1;
  float* enc = out + 8388610;

  int n0 = wave << 6;  // first flat row of this wave's 64 rows
  // zero-stream this wave's own encodings region (64 rows * 1024 f32 = 32768 float2)
  // enc byte offset 8388610*4 = 8 (mod 16) -> float2 (8B) stores aligned.
  // One 512B-contiguous store per 2 codes; 512 stores cover the region.
  float2* encz = (float2*)enc + ((size_t)n0 << 9) + lane;
  const float2 z2 = make_float2(0.0f, 0.0f);

  float best = FLT_MAX;
  int bidx = 0;
  const float4* E4 = (const float4*)emb;

  for (int k2 = 0; k2 < 512; ++k2) {
    #pragma unroll
    for (int u = 0; u < 2; ++u) {
      int k = (k2 << 1) + u;
      const float4* ek = E4 + (k << 4);  // block-uniform -> s_load_dwordx16
      float a0 = 0.0f, a1 = 0.0f, a2 = 0.0f, a3 = 0.0f;
      #pragma unroll
      for (int j = 0; j < 16; ++j) {
        float4 ev = ek[j];
        a0 = fmaf(x[(j << 2) + 0], ev.x, a0);
        a1 = fmaf(x[(j << 2) + 1], ev.y, a1);
        a2 = fmaf(x[(j << 2) + 2], ev.z, a2);
        a3 = fmaf(x[(j << 2) + 3], ev.w, a3);
      }
      float acc  = (a0 + a1) + (a2 + a3);
      float t    = x2 + e2w[k];          // fl(x2 + e2) like numpy broadcast
      float dist = fmaf(-2.0f, acc, t);  // == fl(t - fl(2*acc)); 2*acc exact
      if (dist < best) { best = dist; bidx = k; }  // strict < = first-index
    }
    encz[(size_t)k2 << 6] = z2;  // interleaved one-hot zero streaming
  }

  // ---- epilogue: z_q write (NCHW), loss partial, histogram, one-hot 1.0 ----
  // All d indices compile-time constants -> no scratch demotion.
  const float* esel = emb + (bidx << 6);
  float* zqp = zq + (b << 18) + (h << 6) + lane;
  float lsum = 0.0f;
  #pragma unroll
  for (int d = 0; d < 64; ++d) {
    float v = esel[d];           // per-lane gather (256KB table, L2-resident)
    float df = v - x[d];
    lsum = fmaf(df, df, lsum);
    zqp[d << 12] = v;            // coalesced along w
  }
  #pragma unroll
  for (int off = 32; off > 0; off >>= 1) lsum += __shfl_down(lsum, off, 64);
  if (lane == 0) atomicAdd(ws, lsum);
  atomicAdd(&((int*)ws)[1 + bidx], 1);

  // drain the zero stores before overwriting with 1.0 (same-wave region)
  asm volatile("s_waitcnt vmcnt(0)" ::: "memory");
  enc[((size_t)(n0 + lane) << 10) + bidx] = 1.0f;
}

__global__ __launch_bounds__(1024) void vq_fin(const float* __restrict__ ws,
                                               float* __restrict__ out) {
  __shared__ float sm[16];
  int t = threadIdx.x;  // 0..1023 = k
  const int* counts = (const int*)ws + 1;
  float c = (float)counts[t];
  float p = c * (1.0f / 131072.0f);
  float s = p * logf(p + 1e-10f);
  #pragma unroll
  for (int off = 32; off > 0; off >>= 1) s += __shfl_down(s, off, 64);
  if ((t & 63) == 0) sm[t >> 6] = s;
  __syncthreads();
  if (t == 0) {
    float v = 0.0f;
    #pragma unroll
    for (int i = 0; i < 16; ++i) v += sm[i];
    out[8388609] = expf(-v);               // perplexity
    float m = ws[0] / 8388608.0f;          // mean (z_q - z)^2
    out[0] = 0.25f * m + m;                // commitment + e2z
  }
}

extern "C" void kernel_launch(void* const* d_in, const int* in_sizes, int n_in,
                              void* d_out, int out_size, void* d_ws, size_t ws_size,
                              hipStream_t stream) {
  const float* ze  = (const float*)d_in[0];
  const float* emb = (const float*)d_in[1];
  float* out = (float*)d_out;
  float* ws  = (float*)d_ws;   // needs 2049 * 4B ≈ 8.2 KB
  vq_prep<<<4, 256, 0, stream>>>(emb, ws);
  vq_main<<<512, 256, 0, stream>>>(ze, emb, ws, out);
  vq_fin<<<1, 1024, 0, stream>>>(ws, out);
}

// Round 4
// 812.010 us; speedup vs baseline: 1.8410x; 1.4087x over previous
//
#include <hip/hip_runtime.h>
#include <cfloat>

// Problem dims (fixed): z_e [32,64,64,64] NCHW fp32, embedding [1024,64] fp32
// Flat rows n = b*4096 + h*64 + w  (N = 131072, D = 64, K = 1024)
// Out layout (concat, fp32): [0]=vq_loss, [1..8388608]=z_q NCHW,
//                            [8388609]=perplexity, [8388610..]=encodings [N,1024]
// ws layout: ws[0]=loss accum (float), ws[1..1024]=counts (int), ws[1025..2048]=e2 (float)

__global__ __launch_bounds__(256) void vq_prep(const float* __restrict__ emb,
                                               float* __restrict__ ws) {
  #pragma clang fp contract(off)
  int gid = blockIdx.x * 256 + threadIdx.x;   // 0..1023
  if (gid == 0) ws[0] = 0.0f;
  ((int*)ws)[1 + gid] = 0;
  // e2[k] = numpy-pairwise sum of squares over 64 elems
  const float* e = emb + (gid << 6);
  float r[8];
  #pragma unroll
  for (int j = 0; j < 8; ++j) r[j] = e[j] * e[j];
  #pragma unroll
  for (int i = 8; i < 64; i += 8) {
    #pragma unroll
    for (int j = 0; j < 8; ++j) { float s = e[i + j] * e[i + j]; r[j] = r[j] + s; }
  }
  ws[1025 + gid] = ((r[0] + r[1]) + (r[2] + r[3])) + ((r[4] + r[5]) + (r[6] + r[7]));
}

// Block = 4 waves = one 64-row group (b,h). Wave w scans k-slice [256w, 256w+256).
// w comes from readfirstlane -> formally uniform -> emb addresses scalarize to
// s_load (R2 regression fix #1). x[64] pinned via opaque asm -> cannot be
// rematerialized from L1 inside the k-loop (R1/R3 root cause). Epilogue is
// wave-0-only with compile-time x indices (R2 regression fix #2).
__global__ __launch_bounds__(256, 4) void vq_main(const float* __restrict__ ze,
                                                  const float* __restrict__ emb,
                                                  float* __restrict__ ws,
                                                  float* __restrict__ out) {
  __shared__ float sdist[4][64];
  __shared__ int   sidx[4][64];

  int w    = __builtin_amdgcn_readfirstlane(threadIdx.x >> 6);  // uniform slice id
  int lane = threadIdx.x & 63;   // row within group (= spatial w coord)
  int g    = blockIdx.x;         // row group 0..2047
  int b = g >> 6, h = g & 63;
  int n0 = g << 6;               // first flat row of this group

  // ---- load x[64]: z_e[b, d, h, w], coalesced along w per d ----
  const float* xin = ze + (b << 18) + (h << 6) + lane;
  float x[64];
  #pragma unroll
  for (int d = 0; d < 64; ++d) x[d] = xin[d << 12];
  // Pin: asm-defined values can't be rematerialized -> x stays in 64 VGPRs.
  #pragma unroll
  for (int d = 0; d < 64; ++d) asm("" : "+v"(x[d]));

  // ---- x2: replicate numpy pairwise-sum order exactly ----
  float x2;
  {
    #pragma clang fp contract(off)
    float r[8];
    #pragma unroll
    for (int j = 0; j < 8; ++j) r[j] = x[j] * x[j];
    #pragma unroll
    for (int i = 8; i < 64; i += 8) {
      #pragma unroll
      for (int j = 0; j < 8; ++j) { float s = x[i + j] * x[i + j]; r[j] = r[j] + s; }
    }
    x2 = ((r[0] + r[1]) + (r[2] + r[3])) + ((r[4] + r[5]) + (r[6] + r[7]));
  }

  const float* e2w = ws + 1025;
  float* zq  = out + 1;
  float* enc = out + 8388610;

  int k0 = w << 8;               // uniform slice base
  const float4* E4 = (const float4*)emb;

  // zero-stream: wave w zeroes enc[n0+r][k0 .. k0+256) for r=0..63.
  // 64 rows * 128 float2 = 8192 float2 / 64 lanes = 128 stores/lane,
  // one 512B-contiguous store per k2. enc byte offset ≡ 8 (mod 16) -> 8B aligned.
  float2* encz = (float2*)enc + ((size_t)n0 << 9) + (w << 7) + lane;
  const float2 z2 = make_float2(0.0f, 0.0f);

  float best = FLT_MAX;
  int bidx = k0;

  for (int k2 = 0; k2 < 128; ++k2) {
    #pragma unroll
    for (int u = 0; u < 2; ++u) {
      int k = k0 + (k2 << 1) + u;
      const float4* ek = E4 + (k << 4);  // uniform -> s_load
      float a0 = 0.0f, a1 = 0.0f, a2 = 0.0f, a3 = 0.0f;
      #pragma unroll
      for (int j = 0; j < 16; ++j) {
        float4 ev = ek[j];
        a0 = fmaf(x[(j << 2) + 0], ev.x, a0);
        a1 = fmaf(x[(j << 2) + 1], ev.y, a1);
        a2 = fmaf(x[(j << 2) + 2], ev.z, a2);
        a3 = fmaf(x[(j << 2) + 3], ev.w, a3);
      }
      float acc  = (a0 + a1) + (a2 + a3);
      float t    = x2 + e2w[k];          // fl(x2 + e2) like numpy broadcast
      float dist = fmaf(-2.0f, acc, t);  // == fl(t - fl(2*acc)); 2*acc exact
      if (dist < best) { best = dist; bidx = k; }  // strict < = first-index
    }
    encz[((size_t)(k2 >> 1) << 9) + ((k2 & 1) << 6)] = z2;
  }

  // ---- cross-wave argmin combine (slices k-ordered; strict < keeps the
  //      lowest-k winner on ties = numpy first-index argmin) ----
  sdist[w][lane] = best;
  sidx[w][lane]  = bidx;
  __syncthreads();   // also drains all zero-stream stores before 1.0 writes

  float gb = sdist[0][lane];
  int   gi = sidx[0][lane];
  #pragma unroll
  for (int j = 1; j < 4; ++j) {
    float dj = sdist[j][lane];
    int   ij = sidx[j][lane];
    if (dj < gb) { gb = dj; gi = ij; }
  }

  // ---- epilogue: wave 0 only; all x indices compile-time ----
  if (w == 0) {
    const float* esel = emb + (gi << 6);
    float* zqp = zq + (b << 18) + (h << 6) + lane;
    float lsum = 0.0f;
    #pragma unroll
    for (int d = 0; d < 64; ++d) {
      float v = esel[d];           // per-lane gather (256KB table, L2-resident)
      float df = v - x[d];
      lsum = fmaf(df, df, lsum);
      zqp[d << 12] = v;            // coalesced along w
    }
    #pragma unroll
    for (int off = 32; off > 0; off >>= 1) lsum += __shfl_down(lsum, off, 64);
    if (lane == 0) atomicAdd(ws, lsum);
    atomicAdd(&((int*)ws)[1 + gi], 1);
  }

  // one-hot 1.0: written by the slice-owning wave; its zero store to the same
  // address drained at the barrier above.
  if ((gi >> 8) == w) {
    enc[((size_t)(n0 + lane) << 10) + gi] = 1.0f;
  }
}

__global__ __launch_bounds__(1024) void vq_fin(const float* __restrict__ ws,
                                               float* __restrict__ out) {
  __shared__ float sm[16];
  int t = threadIdx.x;  // 0..1023 = k
  const int* counts = (const int*)ws + 1;
  float c = (float)counts[t];
  float p = c * (1.0f / 131072.0f);
  float s = p * logf(p + 1e-10f);
  #pragma unroll
  for (int off = 32; off > 0; off >>= 1) s += __shfl_down(s, off, 64);
  if ((t & 63) == 0) sm[t >> 6] = s;
  __syncthreads();
  if (t == 0) {
    float v = 0.0f;
    #pragma unroll
    for (int i = 0; i < 16; ++i) v += sm[i];
    out[8388609] = expf(-v);               // perplexity
    float m = ws[0] / 8388608.0f;          // mean (z_q - z)^2
    out[0] = 0.25f * m + m;                // commitment + e2z
  }
}

extern "C" void kernel_launch(void* const* d_in, const int* in_sizes, int n_in,
                              void* d_out, int out_size, void* d_ws, size_t ws_size,
                              hipStream_t stream) {
  const float* ze  = (const float*)d_in[0];
  const float* emb = (const float*)d_in[1];
  float* out = (float*)d_out;
  float* ws  = (float*)d_ws;   // needs 2049 * 4B ≈ 8.2 KB
  vq_prep<<<4, 256, 0, stream>>>(emb, ws);
  vq_main<<<2048, 256, 0, stream>>>(ze, emb, ws, out);
  vq_fin<<<1, 1024, 0, stream>>>(ws, out);
}